// Round 3
// baseline (653.477 us; speedup 1.0000x reference)
//
#include <hip/hip_runtime.h>

#define V 16000
#define E 256
#define H 512
#define HP 516     // padded LDS h row stride (4-float pad: bank groups 4r)
#define BB 8       // batch rows
#define T 12       // lenseq
#define NB 256     // persistent blocks == CUs (1 block/CU at 159KB LDS)
#define TPB 1024   // 16 waves/block
#define CPB 63     // vocab cols per block (256*63 = 16128 >= 16000)
#define AGENT __HIP_MEMORY_SCOPE_AGENT

// Greedy degeneracy verified (R3). Persistent kernel since R4. w_out in LDS
// since R9. R10: phase-B remap (h in VGPRs, kq-swizzle) killed bank conflicts
// (28.5M -> 3.4M) but scalar-NT out write -> 17x write amp -> regression.
// R11: coalesced 252B/wave writer -> still 12x write amp (WRITE 72MB exactly
// = out-size/step) + 35MB RMW/eviction fetch. R12 (this round): controlled
// revert of the WRITER ONLY to R0's exact pattern (the only writer measured
// at 32MB WRITE / 24MB FETCH), sourced from s_e (stride 65, conflict-free);
// keep R11's conflict-free phase-B compute; hoist b_out into VGPRs once
// (step-invariant) so phase B is pure LDS+VALU.

// LDS layout (floats)
constexpr int W_FL   = CPB * 512;            // 32256  swizzled w slice
constexpr int SH_OFF = W_FL;                 // s_h   [8][516]
constexpr int SP_OFF = SH_OFF + BB * HP;     // s_part 64*48 (phase A) / s_e [8][65] (B/C)
constexpr int RS_OFF = SP_OFF + 64 * 48;     // s_rsum [16][8]
constexpr int RV_OFF = RS_OFF + 128;         // s_rval
constexpr int RI_OFF = RV_OFF + 128;         // s_ridx (int)
constexpr int SS_OFF = RI_OFF + 128;         // s_S   [8]
constexpr int XN_OFF = SS_OFF + 8;           // s_Xn  [8] (int)
constexpr int X_OFF  = XN_OFF + 8;           // s_X   [8] (int)
constexpr int SMEM_FL = X_OFF + 8;
constexpr size_t SMEM_BYTES = (size_t)SMEM_FL * 4;   // 159,488 B < 160 KiB

__device__ __forceinline__ float dot4(float4 a, float4 b) {
    return a.x * b.x + a.y * b.y + a.z * b.z + a.w * b.w;
}

__global__ __launch_bounds__(256) void kinit(const float* __restrict__ hidden,
                                             float* __restrict__ hA,
                                             int* __restrict__ leaf,
                                             int* __restrict__ epoch) {
    int idx = blockIdx.x * 256 + threadIdx.x;
    if (idx < BB * H) hA[idx] = hidden[idx];
    if (idx < 64 * 16) leaf[idx] = 0;
    if (idx == 0) epoch[0] = 0;
}

// barrier: leaf arrival (4 blocks/leaf, padded) -> block0 wave0 watches the 64
// leaves -> publishes epoch -> everyone else polls ONE word with ONE lane.
__device__ __forceinline__ void gridbar(int* __restrict__ leaf,
                                        int* __restrict__ epoch, int ep) {
    __syncthreads();
    if (threadIdx.x == 0) {
        int g = blockIdx.x >> 2;
        __hip_atomic_fetch_add(&leaf[g * 16], 1, __ATOMIC_RELEASE, AGENT);
    }
    if (blockIdx.x == 0) {
        if (threadIdx.x < 64) {
            while (__hip_atomic_load(&leaf[threadIdx.x * 16],
                                     __ATOMIC_RELAXED, AGENT) < 4 * ep)
                __builtin_amdgcn_s_sleep(1);
        }
        __syncthreads();
        if (threadIdx.x == 0)
            __hip_atomic_store(epoch, ep, __ATOMIC_RELAXED, AGENT);
    } else {
        if (threadIdx.x == 0) {
            while (__hip_atomic_load(epoch, __ATOMIC_RELAXED, AGENT) < ep)
                __builtin_amdgcn_s_sleep(1);
        }
    }
    __builtin_amdgcn_fence(__ATOMIC_ACQUIRE, "workgroup");
    __syncthreads();
}

__global__ __launch_bounds__(TPB, 4) void kmain(
    const float* __restrict__ emb_tab,
    const float* __restrict__ w_ih,
    const float* __restrict__ w_hh,
    const float* __restrict__ b_ih,
    const float* __restrict__ b_hh,
    const float* __restrict__ w_out,
    const float* __restrict__ b_out,
    float* __restrict__ hA,
    float* __restrict__ hB,
    float* __restrict__ psum,   // [2][8][NB]
    float* __restrict__ pval,
    int* __restrict__ pidx,
    int* __restrict__ leaf,
    int* __restrict__ epoch,
    float* __restrict__ out)
{
    extern __shared__ float smem[];
    float* w_lds  = smem;
    float* s_h    = smem + SH_OFF;
    float* s_part = smem + SP_OFF;
    float* s_e    = smem + SP_OFF;          // alias: phase-B/C e buffer [8][65]
    float* s_rsum = smem + RS_OFF;
    float* s_rval = smem + RV_OFF;
    int*   s_ridx = (int*)(smem + RI_OFF);
    float* s_S    = smem + SS_OFF;
    int*   s_Xn   = (int*)(smem + XN_OFF);
    int*   s_X    = (int*)(smem + X_OFF);

    const int blk = blockIdx.x, tid = threadIdx.x;

    // ---- stage this block's w_out slice into LDS, swizzled, ONCE ----------
    // layout: w_lds[col*512 + (k ^ ((col&7)<<2) ^ (((k>>5)&7)<<2))]
    for (int i = tid; i < CPB * 128; i += TPB) {
        int col = i >> 7;
        int q4  = (i & 127) << 2;
        int vv  = blk * CPB + col;
        if (vv < V) {
            float4 w4 = *(const float4*)(w_out + (size_t)vv * H + q4);
            int sw = q4 ^ ((col & 7) << 2) ^ (((q4 >> 5) & 7) << 2);
            *(float4*)(w_lds + col * 512 + sw) = w4;
        }
    }
    if (tid < BB) s_X[tid] = 1;             // SOS
    __syncthreads();

    // ---- phase-B lane mapping: rh=bits0-1, kq=bits2-5 (16 K-chunks of 32)
    // wave: rowhalf=bit0, col-slot cs=bits1-4; per pass p: col = p*8 + cs
    const int lane = tid & 63;
    const int wv   = tid >> 6;              // 0..15
    const int rh   = lane & 3;
    const int kq   = (lane >> 2) & 15;      // K chunk (32 floats)
    const int rowhalf = wv & 1;
    const int cs   = wv >> 1;               // 0..7
    const int r    = rowhalf * 4 + rh;      // 0..7
    const int xw   = (cs ^ (kq & 7)) << 2;  // w swizzle for this (col-slot,kq)
    const int hswz = (kq & 7) << 2;         // h swizzle for this kq

    // b_out is step-invariant: hoist the 8 per-pass values into VGPRs once
    float bo[8];
#pragma unroll
    for (int p = 0; p < 8; p++) {
        int col = p * 8 + cs;
        int vv  = blk * CPB + col;
        bo[p] = (col < CPB && vv < V) ? b_out[vv] : 0.f;
    }

    for (int t = 0; t < T; t++) {
        const float* h_cur = (t & 1) ? hB : hA;
        float*       h_nxt = (t & 1) ? hA : hB;
        const int par = t & 1;

        // ---------------- phase A: GRU cell (blocks 0..63) ----------------
        if (blk < 64) {                     // stage h_cur into s_h (linear)
            int hr = tid >> 7, k4 = (tid & 127) << 2;
            const unsigned long long* p =
                (const unsigned long long*)(h_cur + hr * H + k4);
            union { unsigned long long u; float f[2]; } c0, c1;
            c0.u = __hip_atomic_load(p,     __ATOMIC_RELAXED, AGENT);
            c1.u = __hip_atomic_load(p + 1, __ATOMIC_RELAXED, AGENT);
            *(float4*)(s_h + hr * HP + k4) =
                make_float4(c0.f[0], c0.f[1], c1.f[0], c1.f[1]);
        }
        __syncthreads();
        if (blk < 64 && tid < 512) {
            const int jl = tid >> 6;        // 0..7
            const int ar = (tid >> 3) & 7;  // row
            const int kq8 = tid & 7;        // K split 8
            const int j  = blk * 8 + jl;
            const int pair = jl * 8 + ar;
            float gir = 0.f, giz = 0.f, gin = 0.f, ghr = 0.f, ghz = 0.f, ghn = 0.f;
            {
                const float* erow = emb_tab + (size_t)s_X[ar] * E;
                const float* w0 = w_ih + (size_t)j * E;
                const float* w1 = w0 + (size_t)H * E;
                const float* w2 = w1 + (size_t)H * E;
                const int k0 = kq8 * (E / 8);
                for (int k = 0; k < E / 8; k += 4) {
                    float4 ev = *(const float4*)(erow + k0 + k);
                    gir += dot4(*(const float4*)(w0 + k0 + k), ev);
                    giz += dot4(*(const float4*)(w1 + k0 + k), ev);
                    gin += dot4(*(const float4*)(w2 + k0 + k), ev);
                }
            }
            {
                const float* hrow = s_h + ar * HP;
                const float* w0 = w_hh + (size_t)j * H;
                const float* w1 = w0 + (size_t)H * H;
                const float* w2 = w1 + (size_t)H * H;
                const int k0 = kq8 * (H / 8);
                for (int k = 0; k < H / 8; k += 4) {
                    float4 hv = *(const float4*)(hrow + k0 + k);
                    ghr += dot4(*(const float4*)(w0 + k0 + k), hv);
                    ghz += dot4(*(const float4*)(w1 + k0 + k), hv);
                    ghn += dot4(*(const float4*)(w2 + k0 + k), hv);
                }
            }
            float* sp = s_part + pair * 48;
            sp[0 * 8 + kq8] = gir; sp[1 * 8 + kq8] = giz; sp[2 * 8 + kq8] = gin;
            sp[3 * 8 + kq8] = ghr; sp[4 * 8 + kq8] = ghz; sp[5 * 8 + kq8] = ghn;
        }
        __syncthreads();
        if (blk < 64 && tid < 512 && (tid & 7) == 0) {
            const int pair = (tid >> 6) * 8 + ((tid >> 3) & 7);
            const int jl = pair >> 3, ar = pair & 7;
            const int j  = blk * 8 + jl;
            const float* sp2 = s_part + pair * 48;
            float G[6];
#pragma unroll
            for (int gg = 0; gg < 6; gg++) {
                float s = 0.f;
#pragma unroll
                for (int q = 0; q < 8; q++) s += sp2[gg * 8 + q];
                G[gg] = s;
            }
            float ir  = G[0] + b_ih[j],         hr_ = G[3] + b_hh[j];
            float iz  = G[1] + b_ih[H + j],     hz  = G[4] + b_hh[H + j];
            float inn = G[2] + b_ih[2 * H + j], hn  = G[5] + b_hh[2 * H + j];
            float rg = 1.f / (1.f + __expf(-(ir + hr_)));
            float zg = 1.f / (1.f + __expf(-(iz + hz)));
            float ng = tanhf(inn + rg * hn);
            float ho = s_h[ar * HP + j];
            int xr = s_X[ar];
            bool dn = (xr == 0) || (xr == 2);
            float hv = dn ? ho : ((1.f - zg) * ng + zg * ho);
            __hip_atomic_store(&h_nxt[ar * H + j], hv, __ATOMIC_RELAXED, AGENT);
        }
        gridbar(leaf, epoch, 2 * t + 1);

        // -------- phase B: logits from LDS-resident w ----------------------
        {   // stage h_nxt, kq-swizzled (layout: s_h[hr*HP + (k ^ ((k>>5&7)<<2))])
            int hr = tid >> 7, k4 = (tid & 127) << 2;
            const unsigned long long* p =
                (const unsigned long long*)(h_nxt + hr * H + k4);
            union { unsigned long long u; float f[2]; } c0, c1;
            c0.u = __hip_atomic_load(p,     __ATOMIC_RELAXED, AGENT);
            c1.u = __hip_atomic_load(p + 1, __ATOMIC_RELAXED, AGENT);
            int sw = k4 ^ (((k4 >> 5) & 7) << 2);
            *(float4*)(s_h + hr * HP + sw) =
                make_float4(c0.f[0], c0.f[1], c1.f[0], c1.f[1]);
        }
        __syncthreads();
        {
            // h chunk -> 32 VGPRs, read ONCE per step
            float4 hreg[8];
            const float* hb = s_h + r * HP + kq * 32;
#pragma unroll
            for (int i = 0; i < 8; i++)
                hreg[i] = *(const float4*)(hb + ((4 * i) ^ hswz));

            float s_acc = 0.f, bv = -1.f; int bi = 0x7fffffff;
#pragma unroll
            for (int p = 0; p < 8; p++) {
                const int col = p * 8 + cs;
                const int vv  = blk * CPB + col;
                const bool okp = (col < CPB) && (vv < V);
                const int cc = okp ? col : 0;       // clamp for LDS bounds
                const float* wb = w_lds + cc * 512 + kq * 32;
                float acc = 0.f;
#pragma unroll
                for (int i = 0; i < 8; i++) {
                    float4 w4 = *(const float4*)(wb + ((4 * i) ^ xw));
                    acc += dot4(w4, hreg[i]);
                }
                // full-K sum across the 16 kq lanes (bits 2-5); butterfly is
                // commutative-add -> bitwise identical on every lane
                acc += __shfl_xor(acc, 4, 64);
                acc += __shfl_xor(acc, 8, 64);
                acc += __shfl_xor(acc, 16, 64);
                acc += __shfl_xor(acc, 32, 64);
                float ee = okp ? __expf(acc + bo[p]) : 0.f;
                if (kq == 0) s_e[r * 65 + col] = ee;  // stash for phase-C write
                s_acc += ee;
                if (ee > bv) { bv = ee; bi = vv; }  // earlier pass = smaller v
            }
            if (kq == 0) {                  // designated: real per-r results
                s_rsum[wv * 8 + r] = s_acc;
                s_rval[wv * 8 + r] = bv;
                s_ridx[wv * 8 + r] = bi;
            } else if (kq == 1) {           // neutral fill for other row-half
                int ro = (1 - rowhalf) * 4 + rh;
                s_rsum[wv * 8 + ro] = 0.f;
                s_rval[wv * 8 + ro] = -1.f;
                s_ridx[wv * 8 + ro] = 0x7fffffff;
            }
        }
        __syncthreads();
        if (tid < 64) {                     // reduce 16 waves -> per-row, store
            float s  = s_rsum[tid] + s_rsum[tid + 64];
            float av = s_rval[tid], bv2 = s_rval[tid + 64];
            int   ai = s_ridx[tid], bi2 = s_ridx[tid + 64];
            float bv = av; int bi = ai;
            if (bv2 > bv || (bv2 == bv && bi2 < bi)) { bv = bv2; bi = bi2; }
#pragma unroll
            for (int m = 8; m <= 32; m <<= 1) {
                s += __shfl_xor(s, m, 64);
                float ov = __shfl_xor(bv, m, 64);
                int   oi = __shfl_xor(bi, m, 64);
                if (ov > bv || (ov == bv && oi < bi)) { bv = ov; bi = oi; }
            }
            if (tid < 8) {
                int o = (par * 8 + tid) * NB + blk;
                __hip_atomic_store(&psum[o], s,  __ATOMIC_RELAXED, AGENT);
                __hip_atomic_store(&pval[o], bv, __ATOMIC_RELAXED, AGENT);
                __hip_atomic_store(&pidx[o], bi, __ATOMIC_RELAXED, AGENT);
            }
        }
        gridbar(leaf, epoch, 2 * t + 2);

        // ------- phase C: redundant global reduce + out write + x update ---
        if (wv < 8) {
            const int base = (par * 8 + wv) * NB;
            float s = 0.f, bv = -1.f; int bi = 0x7fffffff;
#pragma unroll
            for (int c = 0; c < 4; c++) {
                int o = base + lane + 64 * c;
                s += __hip_atomic_load(&psum[o], __ATOMIC_RELAXED, AGENT);
                float ov = __hip_atomic_load(&pval[o], __ATOMIC_RELAXED, AGENT);
                int   oi = __hip_atomic_load(&pidx[o], __ATOMIC_RELAXED, AGENT);
                if (ov > bv || (ov == bv && oi < bi)) { bv = ov; bi = oi; }
            }
            for (int m = 1; m < 64; m <<= 1) {
                s += __shfl_xor(s, m, 64);
                float ov = __shfl_xor(bv, m, 64);
                int   oi = __shfl_xor(bi, m, 64);
                if (ov > bv || (ov == bv && oi < bi)) { bv = ov; bi = oi; }
            }
            if (lane == 0) { s_S[wv] = s; s_Xn[wv] = bi; }
        }
        __syncthreads();
        {   // out write: R0's exact pattern (measured 32MB WRITE / 24MB FETCH)
            float* out_t = out + (size_t)t * BB * V;
            int r0    = lane & 7;
            int kh0   = (lane >> 3) & 1;
            int colw0 = (lane >> 4) & 3;
            int col0  = wv * 4 + colw0;
            int v0    = blk * CPB + col0;
            if (kh0 == 0 && col0 < CPB && v0 < V) {
                int xr = s_X[r0];
                bool dn = (xr == 0) || (xr == 2);
                float val = dn ? ((v0 == 0) ? 1.f : 0.f)
                               : s_e[r0 * 65 + col0] * (1.f / s_S[r0]);
                __builtin_nontemporal_store(val, out_t + r0 * V + v0);
            }
        }
        __syncthreads();
        if (tid < 8) {
            int xo = s_X[tid];
            s_X[tid] = ((xo == 0) || (xo == 2)) ? 0 : s_Xn[tid];
        }
        __syncthreads();
    }
}

extern "C" void kernel_launch(void* const* d_in, const int* in_sizes, int n_in,
                              void* d_out, int out_size, void* d_ws, size_t ws_size,
                              hipStream_t stream) {
    (void)in_sizes; (void)n_in; (void)out_size; (void)ws_size;
    const float* hidden    = (const float*)d_in[0];
    const float* embedding = (const float*)d_in[1];
    const float* w_ih      = (const float*)d_in[2];
    const float* w_hh      = (const float*)d_in[3];
    const float* b_ih      = (const float*)d_in[4];
    const float* b_hh      = (const float*)d_in[5];
    const float* w_out     = (const float*)d_in[6];
    const float* b_out     = (const float*)d_in[7];
    float* out = (float*)d_out;

    float* ws    = (float*)d_ws;
    float* hA    = ws;                        // 4096
    float* hB    = hA + BB * H;               // 4096
    float* psum  = hB + BB * H;               // 2*8*NB
    float* pval  = psum + 2 * 8 * NB;         // 2*8*NB
    int*   pidx  = (int*)(pval + 2 * 8 * NB); // 2*8*NB
    int*   leaf  = pidx + 2 * 8 * NB;         // 64*16 padded counters
    int*   epoch = leaf + 64 * 16;            // 1

    hipFuncSetAttribute((const void*)kmain,
        hipFuncAttributeMaxDynamicSharedMemorySize,
        (int)SMEM_BYTES);

    kinit<<<16, 256, 0, stream>>>(hidden, hA, leaf, epoch);
    kmain<<<NB, TPB, SMEM_BYTES, stream>>>(embedding, w_ih, w_hh, b_ih, b_hh,
                                           w_out, b_out, hA, hB, psum, pval,
                                           pidx, leaf, epoch, out);
}

// Round 5
// 576.675 us; speedup vs baseline: 1.1332x; 1.1332x over previous
//
#include <hip/hip_runtime.h>

#define V 16000
#define E 256
#define H 512
#define HP 516     // padded LDS h row stride (4-float pad: bank groups 4r)
#define BB 8       // batch rows
#define T 12       // lenseq
#define NB 250     // persistent blocks: 250*64 == 16000 exactly (1 block/CU)
#define NBS 256    // psum/pval/pidx stride (padded)
#define TPB 1024   // 16 waves/block
#define CPB 64     // vocab cols per block: 64*4B = 256B row slice, LINE-ALIGNED
#define AGENT __HIP_MEMORY_SCOPE_AGENT

typedef float vfloat4 __attribute__((ext_vector_type(4)));  // NT-store-able

// Greedy degeneracy verified (R3). Persistent kernel since R4. w_out in LDS
// since R9. R10-R12 lesson: scalar-NT partial-line out writes amplify 5-14x
// (WRITE 32-103MB for a 6.1MB output) with timing-dependent variance, and the
// agent-release at each gridbar stalls on those scattered RMWs. R13/R14:
// CPB 63->64, NB 256->250 (250*64 == V exactly). Every out line is
// 64B-aligned, fully covered by ONE block, written by ONE float4-NT store.
// Phase-B guards vanish (all cols valid). Conflict-free phase B + bo hoist
// kept from R11/R12. R14 fixes R13's compile error (NT store needs a native
// ext_vector_type, not HIP_vector_type float4).

// LDS layout (floats)
constexpr int W_FL   = CPB * 512;            // 32768  swizzled w slice (128KB)
constexpr int SH_OFF = W_FL;                 // s_h   [8][516]
constexpr int SP_OFF = SH_OFF + BB * HP;     // s_part 64*48 (A) / s_e [8][65] (B/C)
constexpr int RS_OFF = SP_OFF + 64 * 48;     // s_rsum [16][8]
constexpr int RV_OFF = RS_OFF + 128;         // s_rval
constexpr int RI_OFF = RV_OFF + 128;         // s_ridx (int)
constexpr int SS_OFF = RI_OFF + 128;         // s_S   [8]
constexpr int XN_OFF = SS_OFF + 8;           // s_Xn  [8] (int)
constexpr int X_OFF  = XN_OFF + 8;           // s_X   [8] (int)
constexpr int SMEM_FL = X_OFF + 8;
constexpr size_t SMEM_BYTES = (size_t)SMEM_FL * 4;   // 161,504 B < 160 KiB

__device__ __forceinline__ float dot4(float4 a, float4 b) {
    return a.x * b.x + a.y * b.y + a.z * b.z + a.w * b.w;
}

__global__ __launch_bounds__(256) void kinit(const float* __restrict__ hidden,
                                             float* __restrict__ hA,
                                             int* __restrict__ leaf,
                                             int* __restrict__ epoch) {
    int idx = blockIdx.x * 256 + threadIdx.x;
    if (idx < BB * H) hA[idx] = hidden[idx];
    if (idx < 64 * 16) leaf[idx] = 0;
    if (idx == 0) epoch[0] = 0;
}

// barrier: leaf arrival (63 leaves: blk>>2; leaf 62 has 2 blocks) -> block0
// wave0 watches leaves -> publishes epoch -> everyone else polls ONE word.
__device__ __forceinline__ void gridbar(int* __restrict__ leaf,
                                        int* __restrict__ epoch, int ep) {
    __syncthreads();
    if (threadIdx.x == 0) {
        int g = blockIdx.x >> 2;
        __hip_atomic_fetch_add(&leaf[g * 16], 1, __ATOMIC_RELEASE, AGENT);
    }
    if (blockIdx.x == 0) {
        if (threadIdx.x < 63) {
            int expct = (threadIdx.x == 62) ? 2 : 4;   // 62*4 + 2 = 250
            while (__hip_atomic_load(&leaf[threadIdx.x * 16],
                                     __ATOMIC_RELAXED, AGENT) < expct * ep)
                __builtin_amdgcn_s_sleep(1);
        }
        __syncthreads();
        if (threadIdx.x == 0)
            __hip_atomic_store(epoch, ep, __ATOMIC_RELAXED, AGENT);
    } else {
        if (threadIdx.x == 0) {
            while (__hip_atomic_load(epoch, __ATOMIC_RELAXED, AGENT) < ep)
                __builtin_amdgcn_s_sleep(1);
        }
    }
    __builtin_amdgcn_fence(__ATOMIC_ACQUIRE, "workgroup");
    __syncthreads();
}

__global__ __launch_bounds__(TPB, 4) void kmain(
    const float* __restrict__ emb_tab,
    const float* __restrict__ w_ih,
    const float* __restrict__ w_hh,
    const float* __restrict__ b_ih,
    const float* __restrict__ b_hh,
    const float* __restrict__ w_out,
    const float* __restrict__ b_out,
    float* __restrict__ hA,
    float* __restrict__ hB,
    float* __restrict__ psum,   // [2][8][NBS]
    float* __restrict__ pval,
    int* __restrict__ pidx,
    int* __restrict__ leaf,
    int* __restrict__ epoch,
    float* __restrict__ out)
{
    extern __shared__ float smem[];
    float* w_lds  = smem;
    float* s_h    = smem + SH_OFF;
    float* s_part = smem + SP_OFF;
    float* s_e    = smem + SP_OFF;          // alias: phase-B/C e buffer [8][65]
    float* s_rsum = smem + RS_OFF;
    float* s_rval = smem + RV_OFF;
    int*   s_ridx = (int*)(smem + RI_OFF);
    float* s_S    = smem + SS_OFF;
    int*   s_Xn   = (int*)(smem + XN_OFF);
    int*   s_X    = (int*)(smem + X_OFF);

    const int blk = blockIdx.x, tid = threadIdx.x;

    // ---- stage this block's w_out slice into LDS, swizzled, ONCE ----------
    // layout: w_lds[col*512 + (k ^ ((col&7)<<2) ^ (((k>>5)&7)<<2))]
    for (int i = tid; i < CPB * 128; i += TPB) {
        int col = i >> 7;
        int q4  = (i & 127) << 2;
        int vv  = blk * CPB + col;          // always < V (250*64 == 16000)
        float4 w4 = *(const float4*)(w_out + (size_t)vv * H + q4);
        int sw = q4 ^ ((col & 7) << 2) ^ (((q4 >> 5) & 7) << 2);
        *(float4*)(w_lds + col * 512 + sw) = w4;
    }
    if (tid < BB) s_X[tid] = 1;             // SOS
    __syncthreads();

    // ---- phase-B lane mapping: rh=bits0-1, kq=bits2-5 (16 K-chunks of 32)
    // wave: rowhalf=bit0, col-slot cs=bits1-4; per pass p: col = p*8 + cs
    const int lane = tid & 63;
    const int wv   = tid >> 6;              // 0..15
    const int rh   = lane & 3;
    const int kq   = (lane >> 2) & 15;      // K chunk (32 floats)
    const int rowhalf = wv & 1;
    const int cs   = wv >> 1;               // 0..7
    const int r    = rowhalf * 4 + rh;      // 0..7
    const int xw   = (cs ^ (kq & 7)) << 2;  // w swizzle for this (col-slot,kq)
    const int hswz = (kq & 7) << 2;         // h swizzle for this kq

    // b_out is step-invariant: hoist the 8 per-pass values into VGPRs once
    float bo[8];
#pragma unroll
    for (int p = 0; p < 8; p++) bo[p] = b_out[blk * CPB + p * 8 + cs];

    for (int t = 0; t < T; t++) {
        const float* h_cur = (t & 1) ? hB : hA;
        float*       h_nxt = (t & 1) ? hA : hB;
        const int par = t & 1;

        // ---------------- phase A: GRU cell (blocks 0..63) ----------------
        if (blk < 64) {                     // stage h_cur into s_h (linear)
            int hr = tid >> 7, k4 = (tid & 127) << 2;
            const unsigned long long* p =
                (const unsigned long long*)(h_cur + hr * H + k4);
            union { unsigned long long u; float f[2]; } c0, c1;
            c0.u = __hip_atomic_load(p,     __ATOMIC_RELAXED, AGENT);
            c1.u = __hip_atomic_load(p + 1, __ATOMIC_RELAXED, AGENT);
            *(float4*)(s_h + hr * HP + k4) =
                make_float4(c0.f[0], c0.f[1], c1.f[0], c1.f[1]);
        }
        __syncthreads();
        if (blk < 64 && tid < 512) {
            const int jl = tid >> 6;        // 0..7
            const int ar = (tid >> 3) & 7;  // row
            const int kq8 = tid & 7;        // K split 8
            const int j  = blk * 8 + jl;
            const int pair = jl * 8 + ar;
            float gir = 0.f, giz = 0.f, gin = 0.f, ghr = 0.f, ghz = 0.f, ghn = 0.f;
            {
                const float* erow = emb_tab + (size_t)s_X[ar] * E;
                const float* w0 = w_ih + (size_t)j * E;
                const float* w1 = w0 + (size_t)H * E;
                const float* w2 = w1 + (size_t)H * E;
                const int k0 = kq8 * (E / 8);
                for (int k = 0; k < E / 8; k += 4) {
                    float4 ev = *(const float4*)(erow + k0 + k);
                    gir += dot4(*(const float4*)(w0 + k0 + k), ev);
                    giz += dot4(*(const float4*)(w1 + k0 + k), ev);
                    gin += dot4(*(const float4*)(w2 + k0 + k), ev);
                }
            }
            {
                const float* hrow = s_h + ar * HP;
                const float* w0 = w_hh + (size_t)j * H;
                const float* w1 = w0 + (size_t)H * H;
                const float* w2 = w1 + (size_t)H * H;
                const int k0 = kq8 * (H / 8);
                for (int k = 0; k < H / 8; k += 4) {
                    float4 hv = *(const float4*)(hrow + k0 + k);
                    ghr += dot4(*(const float4*)(w0 + k0 + k), hv);
                    ghz += dot4(*(const float4*)(w1 + k0 + k), hv);
                    ghn += dot4(*(const float4*)(w2 + k0 + k), hv);
                }
            }
            float* sp = s_part + pair * 48;
            sp[0 * 8 + kq8] = gir; sp[1 * 8 + kq8] = giz; sp[2 * 8 + kq8] = gin;
            sp[3 * 8 + kq8] = ghr; sp[4 * 8 + kq8] = ghz; sp[5 * 8 + kq8] = ghn;
        }
        __syncthreads();
        if (blk < 64 && tid < 512 && (tid & 7) == 0) {
            const int pair = (tid >> 6) * 8 + ((tid >> 3) & 7);
            const int jl = pair >> 3, ar = pair & 7;
            const int j  = blk * 8 + jl;
            const float* sp2 = s_part + pair * 48;
            float G[6];
#pragma unroll
            for (int gg = 0; gg < 6; gg++) {
                float s = 0.f;
#pragma unroll
                for (int q = 0; q < 8; q++) s += sp2[gg * 8 + q];
                G[gg] = s;
            }
            float ir  = G[0] + b_ih[j],         hr_ = G[3] + b_hh[j];
            float iz  = G[1] + b_ih[H + j],     hz  = G[4] + b_hh[H + j];
            float inn = G[2] + b_ih[2 * H + j], hn  = G[5] + b_hh[2 * H + j];
            float rg = 1.f / (1.f + __expf(-(ir + hr_)));
            float zg = 1.f / (1.f + __expf(-(iz + hz)));
            float ng = tanhf(inn + rg * hn);
            float ho = s_h[ar * HP + j];
            int xr = s_X[ar];
            bool dn = (xr == 0) || (xr == 2);
            float hv = dn ? ho : ((1.f - zg) * ng + zg * ho);
            __hip_atomic_store(&h_nxt[ar * H + j], hv, __ATOMIC_RELAXED, AGENT);
        }
        gridbar(leaf, epoch, 2 * t + 1);

        // -------- phase B: logits from LDS-resident w ----------------------
        {   // stage h_nxt, kq-swizzled (layout: s_h[hr*HP + (k ^ ((k>>5&7)<<2))])
            int hr = tid >> 7, k4 = (tid & 127) << 2;
            const unsigned long long* p =
                (const unsigned long long*)(h_nxt + hr * H + k4);
            union { unsigned long long u; float f[2]; } c0, c1;
            c0.u = __hip_atomic_load(p,     __ATOMIC_RELAXED, AGENT);
            c1.u = __hip_atomic_load(p + 1, __ATOMIC_RELAXED, AGENT);
            int sw = k4 ^ (((k4 >> 5) & 7) << 2);
            *(float4*)(s_h + hr * HP + sw) =
                make_float4(c0.f[0], c0.f[1], c1.f[0], c1.f[1]);
        }
        __syncthreads();
        {
            // h chunk -> 32 VGPRs, read ONCE per step
            float4 hreg[8];
            const float* hb = s_h + r * HP + kq * 32;
#pragma unroll
            for (int i = 0; i < 8; i++)
                hreg[i] = *(const float4*)(hb + ((4 * i) ^ hswz));

            float s_acc = 0.f, bv = -1.f; int bi = 0x7fffffff;
#pragma unroll
            for (int p = 0; p < 8; p++) {
                const int col = p * 8 + cs;
                const int vv  = blk * CPB + col;
                const float* wb = w_lds + col * 512 + kq * 32;
                float acc = 0.f;
#pragma unroll
                for (int i = 0; i < 8; i++) {
                    float4 w4 = *(const float4*)(wb + ((4 * i) ^ xw));
                    acc += dot4(w4, hreg[i]);
                }
                // full-K sum across the 16 kq lanes (bits 2-5); butterfly is
                // commutative-add -> bitwise identical on every lane
                acc += __shfl_xor(acc, 4, 64);
                acc += __shfl_xor(acc, 8, 64);
                acc += __shfl_xor(acc, 16, 64);
                acc += __shfl_xor(acc, 32, 64);
                float ee = __expf(acc + bo[p]);
                if (kq == 0) s_e[r * 65 + col] = ee;  // stash for phase-C write
                s_acc += ee;
                if (ee > bv) { bv = ee; bi = vv; }  // earlier pass = smaller v
            }
            if (kq == 0) {                  // designated: real per-r results
                s_rsum[wv * 8 + r] = s_acc;
                s_rval[wv * 8 + r] = bv;
                s_ridx[wv * 8 + r] = bi;
            } else if (kq == 1) {           // neutral fill for other row-half
                int ro = (1 - rowhalf) * 4 + rh;
                s_rsum[wv * 8 + ro] = 0.f;
                s_rval[wv * 8 + ro] = -1.f;
                s_ridx[wv * 8 + ro] = 0x7fffffff;
            }
        }
        __syncthreads();
        if (tid < 64) {                     // reduce 16 waves -> per-row, store
            float s  = s_rsum[tid] + s_rsum[tid + 64];
            float av = s_rval[tid], bv2 = s_rval[tid + 64];
            int   ai = s_ridx[tid], bi2 = s_ridx[tid + 64];
            float bv = av; int bi = ai;
            if (bv2 > bv || (bv2 == bv && bi2 < bi)) { bv = bv2; bi = bi2; }
#pragma unroll
            for (int m = 8; m <= 32; m <<= 1) {
                s += __shfl_xor(s, m, 64);
                float ov = __shfl_xor(bv, m, 64);
                int   oi = __shfl_xor(bi, m, 64);
                if (ov > bv || (ov == bv && oi < bi)) { bv = ov; bi = oi; }
            }
            if (tid < 8) {
                int o = (par * 8 + tid) * NBS + blk;
                __hip_atomic_store(&psum[o], s,  __ATOMIC_RELAXED, AGENT);
                __hip_atomic_store(&pval[o], bv, __ATOMIC_RELAXED, AGENT);
                __hip_atomic_store(&pidx[o], bi, __ATOMIC_RELAXED, AGENT);
            }
        }
        gridbar(leaf, epoch, 2 * t + 2);

        // ------- phase C: redundant global reduce + out write + x update ---
        if (wv < 8) {
            const int base = (par * 8 + wv) * NBS;
            float s = 0.f, bv = -1.f; int bi = 0x7fffffff;
#pragma unroll
            for (int c = 0; c < 4; c++) {
                int idx = lane + 64 * c;
                if (idx < NB) {
                    int o = base + idx;
                    s += __hip_atomic_load(&psum[o], __ATOMIC_RELAXED, AGENT);
                    float ov = __hip_atomic_load(&pval[o], __ATOMIC_RELAXED, AGENT);
                    int   oi = __hip_atomic_load(&pidx[o], __ATOMIC_RELAXED, AGENT);
                    if (ov > bv || (ov == bv && oi < bi)) { bv = ov; bi = oi; }
                }
            }
            for (int m = 1; m < 64; m <<= 1) {
                s += __shfl_xor(s, m, 64);
                float ov = __shfl_xor(bv, m, 64);
                int   oi = __shfl_xor(bi, m, 64);
                if (ov > bv || (ov == bv && oi < bi)) { bv = ov; bi = oi; }
            }
            if (lane == 0) { s_S[wv] = s; s_Xn[wv] = bi; }
        }
        __syncthreads();
        {   // out write: FULL-LINE vfloat4 NT stores. Row slice = 256B aligned.
            float* out_t = out + (size_t)t * BB * V;
            if (tid < 128) {
                int row = tid >> 4;         // 0..7
                int c4  = (tid & 15) << 2;  // 0,4,...,60
                int xr = s_X[row];
                bool dn = (xr == 0) || (xr == 2);
                float inv = 1.f / s_S[row];
                int vbase = blk * CPB + c4;
                vfloat4 o4;
                o4.x = dn ? ((vbase + 0 == 0) ? 1.f : 0.f) : s_e[row * 65 + c4 + 0] * inv;
                o4.y = dn ? ((vbase + 1 == 0) ? 1.f : 0.f) : s_e[row * 65 + c4 + 1] * inv;
                o4.z = dn ? ((vbase + 2 == 0) ? 1.f : 0.f) : s_e[row * 65 + c4 + 2] * inv;
                o4.w = dn ? ((vbase + 3 == 0) ? 1.f : 0.f) : s_e[row * 65 + c4 + 3] * inv;
                __builtin_nontemporal_store(o4,
                    (vfloat4*)(out_t + (size_t)row * V + vbase));
            }
        }
        __syncthreads();
        if (tid < 8) {
            int xo = s_X[tid];
            s_X[tid] = ((xo == 0) || (xo == 2)) ? 0 : s_Xn[tid];
        }
        __syncthreads();
    }
}

extern "C" void kernel_launch(void* const* d_in, const int* in_sizes, int n_in,
                              void* d_out, int out_size, void* d_ws, size_t ws_size,
                              hipStream_t stream) {
    (void)in_sizes; (void)n_in; (void)out_size; (void)ws_size;
    const float* hidden    = (const float*)d_in[0];
    const float* embedding = (const float*)d_in[1];
    const float* w_ih      = (const float*)d_in[2];
    const float* w_hh      = (const float*)d_in[3];
    const float* b_ih      = (const float*)d_in[4];
    const float* b_hh      = (const float*)d_in[5];
    const float* w_out     = (const float*)d_in[6];
    const float* b_out     = (const float*)d_in[7];
    float* out = (float*)d_out;

    float* ws    = (float*)d_ws;
    float* hA    = ws;                        // 4096
    float* hB    = hA + BB * H;               // 4096
    float* psum  = hB + BB * H;               // 2*8*NBS
    float* pval  = psum + 2 * 8 * NBS;        // 2*8*NBS
    int*   pidx  = (int*)(pval + 2 * 8 * NBS);// 2*8*NBS
    int*   leaf  = pidx + 2 * 8 * NBS;        // 64*16 padded counters
    int*   epoch = leaf + 64 * 16;            // 1

    hipFuncSetAttribute((const void*)kmain,
        hipFuncAttributeMaxDynamicSharedMemorySize,
        (int)SMEM_BYTES);

    kinit<<<16, 256, 0, stream>>>(hidden, hA, leaf, epoch);
    kmain<<<NB, TPB, SMEM_BYTES, stream>>>(embedding, w_ih, w_hh, b_ih, b_hh,
                                           w_out, b_out, hA, hB, psum, pval,
                                           pidx, leaf, epoch, out);
}